// Round 1
// baseline (844.310 us; speedup 1.0000x reference)
//
#include <hip/hip_runtime.h>
#include <math.h>

#define T_STEPS 22
#define F_IN    12
#define HID     32
#define HSTRIDE 33   // odd stride: LDS broadcast reads land 2-way/bank = free

__device__ __forceinline__ float fast_sigmoid(float x) {
    // 1/(1+exp(-x)) = 1/(1+exp2(-x*log2e))
    float e = __builtin_amdgcn_exp2f(-1.442695041f * x);
    return __builtin_amdgcn_rcpf(1.0f + e);
}

__device__ __forceinline__ float fast_tanh(float x) {
    // tanh(x) = 1 - 2/(exp(2x)+1); stable at +/-inf (exp2 overflow -> inf -> rcp -> 0)
    float e = __builtin_amdgcn_exp2f(2.885390082f * x);
    float r = __builtin_amdgcn_rcpf(1.0f + e);
    return fmaf(-2.0f, r, 1.0f);
}

// Transpose weights so the inner j-loop reads 32 consecutive floats at a
// wave-uniform address -> s_load_dwordx16 candidates.
// ws layout (floats): bias[128] | WihT[12][128] | WhhT[32][128]
__global__ void prep_kernel(const float* __restrict__ Wih, const float* __restrict__ Whh,
                            const float* __restrict__ bih, const float* __restrict__ bhh,
                            float* __restrict__ ws) {
    int tid = threadIdx.x;
    float* bias = ws;
    float* wihT = ws + 128;
    float* whhT = ws + 128 + F_IN * 128;
    if (tid < 128) bias[tid] = bih[tid] + bhh[tid];
    for (int n = tid; n < F_IN * 128; n += 256) {
        int f = n >> 7, j = n & 127;
        wihT[n] = Wih[j * F_IN + f];
    }
    for (int n = tid; n < HID * 128; n += 256) {
        int k = n >> 7, j = n & 127;
        whhT[n] = Whh[j * HID + k];
    }
}

template <int JB>
__device__ __forceinline__ void gate32(float acc[HID],
                                       const float* __restrict__ bias,
                                       const float* __restrict__ wihT,
                                       const float* __restrict__ whhT,
                                       const float xt[F_IN],
                                       const float* hme, int kmax) {
#pragma unroll
    for (int j = 0; j < HID; ++j) acc[j] = bias[JB + j];
#pragma unroll
    for (int f = 0; f < F_IN; ++f) {
        float xv = xt[f];
#pragma unroll
        for (int j = 0; j < HID; ++j)
            acc[j] = fmaf(wihT[f * 128 + JB + j], xv, acc[j]);
    }
#pragma unroll 4
    for (int k = 0; k < kmax; ++k) {
        float hv = hme[k];   // per-thread LDS row, runtime k (keeps code small)
#pragma unroll
        for (int j = 0; j < HID; ++j)
            acc[j] = fmaf(whhT[k * 128 + JB + j], hv, acc[j]);
    }
}

__global__ void __launch_bounds__(256, 2)
lstm_kernel(const float* __restrict__ x, const float* __restrict__ ws,
            const float* __restrict__ Whead, const float* __restrict__ bhead,
            float* __restrict__ out, int B) {
    const float* __restrict__ bias = ws;
    const float* __restrict__ wihT = ws + 128;
    const float* __restrict__ whhT = ws + 128 + F_IN * 128;

    __shared__ float hsh[256 * HSTRIDE];
    const int tid = threadIdx.x;
    const int b = blockIdx.x * 256 + tid;
    if (b >= B) return;

    float* hme = &hsh[tid * HSTRIDE];

    const float4* __restrict__ xp =
        (const float4*)(x + (size_t)b * (T_STEPS * F_IN));

    float c[HID];
#pragma unroll
    for (int j = 0; j < HID; ++j) c[j] = 0.0f;
#pragma unroll
    for (int j = 0; j < HID; ++j) hme[j] = 0.0f;

    for (int t = 0; t < T_STEPS; ++t) {
        float4 v0 = xp[t * 3 + 0];
        float4 v1 = xp[t * 3 + 1];
        float4 v2 = xp[t * 3 + 2];
        float xt[F_IN] = {v0.x, v0.y, v0.z, v0.w,
                          v1.x, v1.y, v1.z, v1.w,
                          v2.x, v2.y, v2.z, v2.w};
        const int kmax = (t == 0) ? 0 : HID;  // h==0 at t=0: skip recurrent part

        // PyTorch gate order in the 4H axis: i[0:32) f[32:64) g[64:96) o[96:128)
        // Process f -> i -> g -> o to minimize live registers.
        float accf[HID];
        gate32<32>(accf, bias, wihT, whhT, xt, hme, kmax);
#pragma unroll
        for (int j = 0; j < HID; ++j) c[j] *= fast_sigmoid(accf[j]);

        float isv[HID];
        gate32<0>(isv, bias, wihT, whhT, xt, hme, kmax);
#pragma unroll
        for (int j = 0; j < HID; ++j) isv[j] = fast_sigmoid(isv[j]);

        float accg[HID];
        gate32<64>(accg, bias, wihT, whhT, xt, hme, kmax);
#pragma unroll
        for (int j = 0; j < HID; ++j) c[j] = fmaf(isv[j], fast_tanh(accg[j]), c[j]);

        float acco[HID];
        gate32<96>(acco, bias, wihT, whhT, xt, hme, kmax);
#pragma unroll
        for (int j = 0; j < HID; ++j)
            hme[j] = fast_sigmoid(acco[j]) * fast_tanh(c[j]);
    }

    // head: y = h . Whead + bhead ; out = softplus(y)
    float y = bhead[0];
#pragma unroll
    for (int j = 0; j < HID; ++j) y = fmaf(hme[j], Whead[j], y);
    float sp = fmaxf(y, 0.0f) + log1pf(expf(-fabsf(y)));
    out[b] = sp;
}

extern "C" void kernel_launch(void* const* d_in, const int* in_sizes, int n_in,
                              void* d_out, int out_size, void* d_ws, size_t ws_size,
                              hipStream_t stream) {
    const float* x     = (const float*)d_in[0];
    const float* Wih   = (const float*)d_in[1];
    const float* Whh   = (const float*)d_in[2];
    const float* bih   = (const float*)d_in[3];
    const float* bhh   = (const float*)d_in[4];
    const float* Whead = (const float*)d_in[5];
    const float* bhead = (const float*)d_in[6];
    float* out = (float*)d_out;
    float* ws  = (float*)d_ws;

    const int B = in_sizes[0] / (T_STEPS * F_IN);

    hipLaunchKernelGGL(prep_kernel, dim3(1), dim3(256), 0, stream,
                       Wih, Whh, bih, bhh, ws);
    hipLaunchKernelGGL(lstm_kernel, dim3((B + 255) / 256), dim3(256), 0, stream,
                       x, ws, Whead, bhead, out, B);
}

// Round 2
// 117.913 us; speedup vs baseline: 7.1604x; 7.1604x over previous
//
#include <hip/hip_runtime.h>
#include <math.h>

#define T_STEPS 22
#define F_IN    12
#define HID     32

typedef __attribute__((ext_vector_type(8))) short  bf16x8;
typedef __attribute__((ext_vector_type(16))) float f32x16;

union FragU { unsigned int u[4]; bf16x8 v; };

static __device__ __forceinline__ unsigned short f2bf(float x) {
    // f32 -> bf16 round-to-nearest-even
    unsigned int u = __builtin_bit_cast(unsigned int, x);
    return (unsigned short)((u + 0x7fffu + ((u >> 16) & 1u)) >> 16);
}

static __device__ __forceinline__ float fast_sigmoid(float x) {
    float e = __builtin_amdgcn_exp2f(-1.442695041f * x);
    return __builtin_amdgcn_rcpf(1.0f + e);
}
static __device__ __forceinline__ float fast_tanh(float x) {
    // tanh(x) = 1 - 2/(exp2(x*2*log2e)+1); stable at +/-inf
    float e = __builtin_amdgcn_exp2f(2.885390082f * x);
    float r = __builtin_amdgcn_rcpf(1.0f + e);
    return fmaf(-2.0f, r, 1.0f);
}

// ws layout:
//   bytes [0,     4096)  wx_frag: [4 mtiles][64 lanes] x 8 bf16  (A-frag, K=16: feat 0..11, k=12 = fused bias, rest 0)
//   bytes [4096, 12288)  wh_frag: [4 mtiles][2 ktiles][64 lanes] x 8 bf16 (A-frag for h, K=32)
//   bytes [12288,12416)  whead:   [2 hi][16 q] f32, pre-permuted to C-layout rows
__global__ void prep_kernel(const float* __restrict__ Wih, const float* __restrict__ Whh,
                            const float* __restrict__ bih, const float* __restrict__ bhh,
                            const float* __restrict__ Whead, float* __restrict__ ws) {
    const int tid = threadIdx.x;  // 256
    unsigned short* wx = (unsigned short*)ws;
    unsigned short* wh = (unsigned short*)(ws + 1024);
    float* whd = ws + 3072;

    {   // wx: entry = m*64 + lane  (== tid)
        int m = tid >> 6, lane = tid & 63;
        int g = 32 * m + (lane & 31);          // A row = gate index
        int kbase = 8 * (lane >> 5);
        for (int j = 0; j < 8; ++j) {
            int k = kbase + j;
            float v = 0.0f;
            if (k < F_IN)       v = Wih[g * F_IN + k];
            else if (k == F_IN) v = bih[g] + bhh[g];   // bias via constant-1 feature
            wx[tid * 8 + j] = f2bf(v);
        }
    }
    for (int e = tid; e < 4 * 2 * 64; e += 256) {
        int m = e >> 7, kt = (e >> 6) & 1, lane = e & 63;
        int g = 32 * m + (lane & 31);
        int kbase = 16 * kt + 8 * (lane >> 5);
        for (int j = 0; j < 8; ++j)
            wh[e * 8 + j] = f2bf(Whh[g * HID + kbase + j]);
    }
    if (tid < 32) {
        int hi = tid >> 4, q = tid & 15;
        int j = (q & 3) + 8 * (q >> 2) + 4 * hi;   // C-layout row for (q, hi)
        whd[tid] = Whead[j];
    }
}

__global__ void __launch_bounds__(256, 2)
lstm_kernel(const float* __restrict__ x, const float* __restrict__ ws,
            const float* __restrict__ bheadp, float* __restrict__ out, int B) {
    const int lane = threadIdx.x & 63;
    const int wave = threadIdx.x >> 6;
    const int col  = lane & 31;   // batch row within the wave's 32-row tile
    const int hi   = lane >> 5;   // k-group half
    int b = blockIdx.x * 128 + wave * 32 + col;
    const bool valid = (b < B);
    if (b >= B) b = B - 1;

    // Preload weight fragments (uniform across waves; L2-resident)
    const bf16x8* wxp = (const bf16x8*)ws;
    const bf16x8* whp = (const bf16x8*)(ws + 1024);
    bf16x8 wxf[4], whf[4][2];
#pragma unroll
    for (int m = 0; m < 4; ++m) wxf[m] = wxp[m * 64 + lane];
#pragma unroll
    for (int m = 0; m < 4; ++m)
#pragma unroll
        for (int kt = 0; kt < 2; ++kt) whf[m][kt] = whp[(m * 2 + kt) * 64 + lane];

    // x row pointers: hi=0 reads k=0..3 / 4..7 ; hi=1 reads k=8..11 twice
    // (hi=1's second chunk only feeds zero weights; elem 4 is overwritten with 1.0)
    const float* xr1 = x + (size_t)b * (T_STEPS * F_IN) + (hi ? 8 : 0);
    const float* xr2 = x + (size_t)b * (T_STEPS * F_IN) + (hi ? 8 : 4);

    float c[16];
#pragma unroll
    for (int q = 0; q < 16; ++q) c[q] = 0.0f;
    bf16x8 hf0, hf1;
#pragma unroll
    for (int j = 0; j < 8; ++j) { hf0[j] = 0; hf1[j] = 0; }

    float hv[16];
#pragma unroll
    for (int q = 0; q < 16; ++q) hv[q] = 0.0f;

    for (int t = 0; t < T_STEPS; ++t) {
        float4 va = *(const float4*)(xr1 + t * F_IN);
        float4 vb = *(const float4*)(xr2 + t * F_IN);
        FragU xf;
        xf.u[0] = (unsigned)f2bf(va.x) | ((unsigned)f2bf(va.y) << 16);
        xf.u[1] = (unsigned)f2bf(va.z) | ((unsigned)f2bf(va.w) << 16);
        xf.u[2] = (unsigned)f2bf(vb.x) | ((unsigned)f2bf(vb.y) << 16);
        xf.u[3] = (unsigned)f2bf(vb.z) | ((unsigned)f2bf(vb.w) << 16);
        if (hi) xf.u[2] = (xf.u[2] & 0xffff0000u) | 0x3f80u;  // k=12 -> 1.0 (bias)

        f32x16 a0, a1, a2, a3;
#pragma unroll
        for (int q = 0; q < 16; ++q) { a0[q] = 0.f; a1[q] = 0.f; a2[q] = 0.f; a3[q] = 0.f; }

        a0 = __builtin_amdgcn_mfma_f32_32x32x16_bf16(wxf[0], xf.v, a0, 0, 0, 0);
        a1 = __builtin_amdgcn_mfma_f32_32x32x16_bf16(wxf[1], xf.v, a1, 0, 0, 0);
        a2 = __builtin_amdgcn_mfma_f32_32x32x16_bf16(wxf[2], xf.v, a2, 0, 0, 0);
        a3 = __builtin_amdgcn_mfma_f32_32x32x16_bf16(wxf[3], xf.v, a3, 0, 0, 0);
        a0 = __builtin_amdgcn_mfma_f32_32x32x16_bf16(whf[0][0], hf0, a0, 0, 0, 0);
        a1 = __builtin_amdgcn_mfma_f32_32x32x16_bf16(whf[1][0], hf0, a1, 0, 0, 0);
        a2 = __builtin_amdgcn_mfma_f32_32x32x16_bf16(whf[2][0], hf0, a2, 0, 0, 0);
        a3 = __builtin_amdgcn_mfma_f32_32x32x16_bf16(whf[3][0], hf0, a3, 0, 0, 0);
        a0 = __builtin_amdgcn_mfma_f32_32x32x16_bf16(whf[0][1], hf1, a0, 0, 0, 0);
        a1 = __builtin_amdgcn_mfma_f32_32x32x16_bf16(whf[1][1], hf1, a1, 0, 0, 0);
        a2 = __builtin_amdgcn_mfma_f32_32x32x16_bf16(whf[2][1], hf1, a2, 0, 0, 0);
        a3 = __builtin_amdgcn_mfma_f32_32x32x16_bf16(whf[3][1], hf1, a3, 0, 0, 0);

        // elementwise LSTM cell in C-layout registers (i,f,g,o = tiles 0..3)
#pragma unroll
        for (int q = 0; q < 16; ++q) {
            float ig = fast_sigmoid(a0[q]);
            float fg = fast_sigmoid(a1[q]);
            float gg = fast_tanh(a2[q]);
            float og = fast_sigmoid(a3[q]);
            c[q]  = fmaf(fg, c[q], ig * gg);
            hv[q] = og * fast_tanh(c[q]);
        }

        // repack h (C-layout: 16 rows x this lane's batch col) into next step's
        // B-fragments (this lane's batch col x 8 consecutive h-indices).
        // Only exchange needed: lane <-> lane+32.
        unsigned int P[8];
#pragma unroll
        for (int p = 0; p < 8; ++p)
            P[p] = (unsigned)f2bf(hv[2 * p]) | ((unsigned)f2bf(hv[2 * p + 1]) << 16);

        int u0 = hi ? (int)P[0] : (int)P[2];
        int u1 = hi ? (int)P[1] : (int)P[3];
        int u2 = hi ? (int)P[4] : (int)P[6];
        int u3 = hi ? (int)P[5] : (int)P[7];
        int s0 = __shfl_xor(u0, 32, 64);
        int s1 = __shfl_xor(u1, 32, 64);
        int s2 = __shfl_xor(u2, 32, 64);
        int s3 = __shfl_xor(u3, 32, 64);

        FragU t0, t1;
        t0.u[0] = hi ? (unsigned)s0 : P[0];
        t0.u[1] = hi ? (unsigned)s1 : P[1];
        t0.u[2] = hi ? P[2] : (unsigned)s0;
        t0.u[3] = hi ? P[3] : (unsigned)s1;
        t1.u[0] = hi ? (unsigned)s2 : P[4];
        t1.u[1] = hi ? (unsigned)s3 : P[5];
        t1.u[2] = hi ? P[6] : (unsigned)s2;
        t1.u[3] = hi ? P[7] : (unsigned)s3;
        hf0 = t0.v;
        hf1 = t1.v;
    }

    // head: y = h . Whead + bhead ; out = softplus(y)
    const float* whd = ws + 3072 + hi * 16;
    float y = 0.0f;
#pragma unroll
    for (int q = 0; q < 16; ++q) y = fmaf(hv[q], whd[q], y);
    y += __shfl_xor(y, 32, 64);
    y += bheadp[0];
    float sp = fmaxf(y, 0.0f) + log1pf(expf(-fabsf(y)));
    if (valid && hi == 0) out[b] = sp;
}

extern "C" void kernel_launch(void* const* d_in, const int* in_sizes, int n_in,
                              void* d_out, int out_size, void* d_ws, size_t ws_size,
                              hipStream_t stream) {
    const float* x     = (const float*)d_in[0];
    const float* Wih   = (const float*)d_in[1];
    const float* Whh   = (const float*)d_in[2];
    const float* bih   = (const float*)d_in[3];
    const float* bhh   = (const float*)d_in[4];
    const float* Whead = (const float*)d_in[5];
    const float* bhead = (const float*)d_in[6];
    float* out = (float*)d_out;
    float* ws  = (float*)d_ws;

    const int B = in_sizes[0] / (T_STEPS * F_IN);
    const int blocks = (B + 127) / 128;

    hipLaunchKernelGGL(prep_kernel, dim3(1), dim3(256), 0, stream,
                       Wih, Whh, bih, bhh, Whead, ws);
    hipLaunchKernelGGL(lstm_kernel, dim3(blocks), dim3(256), 0, stream,
                       x, ws, bhead, out, B);
}